// Round 9
// baseline (120.801 us; speedup 1.0000x reference)
//
#include <hip/hip_runtime.h>

typedef float f4 __attribute__((ext_vector_type(4)));

constexpr int N_  = 4;
constexpr int C_  = 320;
constexpr int H_  = 80;
constexpr int W_  = 160;
constexpr int G_  = 40;
constexpr int CPG = 8;                       // channels per group
constexpr int D_  = 48;                      // max disparity
constexpr int PAD = 48;                      // zero pad in front of R rows
constexpr int RW  = PAD + W_;                // 208 floats per R row
constexpr int HW  = H_ * W_;                 // channel stride in floats
constexpr int TILES = (W_ / 4) * (D_ / 4);   // 480 4w x 4d tiles per row

__global__ __launch_bounds__(256) void gw_cost_kernel(const float* __restrict__ Lg,
                                                      const float* __restrict__ Rg,
                                                      float* __restrict__ out) {
    __shared__ float Ls[CPG * W_];    // 5120 B
    __shared__ float Rs[CPG * RW];    // 6656 B, rw<48 is zero pad

    const int tid  = threadIdx.x;
    const int lane = tid & 63;
    const int blk  = blockIdx.x;              // ((n*G + g)*H + h)

    const int h = blk % H_;
    const int g = (blk / H_) % G_;
    const int n = blk / (H_ * G_);

    const size_t rowbase = (size_t)(n * C_ + g * CPG) * HW + (size_t)h * W_;

    // ---- EVERY wave zeroes ALL pads and DMAs ALL 16 channel-rows itself. ----
    // Racing writes carry identical bytes (benign); each wave's compute is
    // ordered only on its OWN ds_writes (lgkmcnt) and DMAs (vmcnt) -> NO barrier,
    // no inter-wave convoy. Extra L2 reads (4x inputs) ride the 34.5 TB/s L2 pipe.
    for (int p = lane; p < CPG * (PAD / 4); p += 64) {   // 96 zero f4 per wave
        const int c = p / 12, p4 = p % 12;
        *(f4*)&Rs[c * RW + p4 * 4] = (f4)(0.0f);
    }
    if (lane < 40) {
        #pragma unroll
        for (int c = 0; c < CPG; ++c) {
            const float* gl = Lg + rowbase + (size_t)c * HW + lane * 4;
            const float* gr = Rg + rowbase + (size_t)c * HW + lane * 4;
            __builtin_amdgcn_global_load_lds(
                (const __attribute__((address_space(1))) void*)gl,
                (__attribute__((address_space(3))) void*)&Ls[c * W_], 16, 0, 0);
            __builtin_amdgcn_global_load_lds(
                (const __attribute__((address_space(1))) void*)gr,
                (__attribute__((address_space(3))) void*)&Rs[c * RW + PAD], 16, 0, 0);
        }
    }
    // Wave-local wait: my own DMAs wrote every byte I read below.
    asm volatile("s_waitcnt vmcnt(0)" ::: "memory");
    __builtin_amdgcn_sched_barrier(0);

    // ---- compute (R6's proven 4w x 4d core, unchanged; no __syncthreads) ----
    for (int t = tid; t < TILES; t += 256) {
        const int tw = t / 12;
        const int td = t % 12;
        const int w0 = tw * 4;
        const int d0 = td * 4;
        const int r0 = w0 - d0 + PAD;   // [4, 204]; reads r0-4 .. r0+3 within [0, 207]

        f4 acc0 = (f4)(0.0f), acc1 = (f4)(0.0f), acc2 = (f4)(0.0f), acc3 = (f4)(0.0f);

        #pragma unroll
        for (int c = 0; c < CPG; ++c) {
            const f4 lv = *(const f4*)&Ls[c * W_ + w0];
            const float* rp = &Rs[c * RW + (r0 - 4)];  // 16B-aligned
            const f4 ra = *(const f4*)(rp);
            const f4 rb = *(const f4*)(rp + 4);
            float rr[8];
            #pragma unroll
            for (int k = 0; k < 4; ++k) { rr[k] = ra[k]; rr[4 + k] = rb[k]; }
            // out(w0+i, d0+j) += L[w0+i] * R[r0 + i - j] -> rr[4 + i - j]
            #pragma unroll
            for (int j = 0; j < 4; ++j) {
                acc0[j] += lv[0] * rr[4 + 0 - j];
                acc1[j] += lv[1] * rr[4 + 1 - j];
                acc2[j] += lv[2] * rr[4 + 2 - j];
                acc3[j] += lv[3] * rr[4 + 3 - j];
            }
        }

        float* op = out + (size_t)blk * (W_ * D_) + (size_t)w0 * D_ + d0;
        *(f4*)(op + 0 * D_) = acc0 * 0.125f;
        *(f4*)(op + 1 * D_) = acc1 * 0.125f;
        *(f4*)(op + 2 * D_) = acc2 * 0.125f;
        *(f4*)(op + 3 * D_) = acc3 * 0.125f;
    }
}

extern "C" void kernel_launch(void* const* d_in, const int* in_sizes, int n_in,
                              void* d_out, int out_size, void* d_ws, size_t ws_size,
                              hipStream_t stream) {
    const float* Lg = (const float*)d_in[0];
    const float* Rg = (const float*)d_in[1];
    float* out = (float*)d_out;

    const int nblocks = N_ * G_ * H_;   // 12800 blocks, one per (n, g, h)
    gw_cost_kernel<<<dim3(nblocks), dim3(256), 0, stream>>>(Lg, Rg, out);
}

// Round 10
// 109.638 us; speedup vs baseline: 1.1018x; 1.1018x over previous
//
#include <hip/hip_runtime.h>

typedef float f4 __attribute__((ext_vector_type(4)));

constexpr int N_  = 4;
constexpr int C_  = 320;
constexpr int H_  = 80;
constexpr int W_  = 160;
constexpr int G_  = 40;
constexpr int CPG = 8;                       // channels per group
constexpr int D_  = 48;                      // max disparity
constexpr int PAD = 48;                      // zero pad in front of R rows
constexpr int RW  = PAD + W_;                // 208 floats per R row
constexpr int HW  = H_ * W_;                 // channel stride in floats
constexpr int TILES = (W_ / 4) * (D_ / 8);   // 240 4w x 8d tiles per row

__global__ __launch_bounds__(256) void gw_cost_kernel(const float* __restrict__ Lg,
                                                      const float* __restrict__ Rg,
                                                      float* __restrict__ out) {
    __shared__ float Ls[CPG * W_];    // 5120 B
    __shared__ float Rs[CPG * RW];    // 6656 B, rw<48 is zero pad   (11.8 KB total)

    const int tid  = threadIdx.x;
    const int wid  = tid >> 6;
    const int lane = tid & 63;
    const int blk  = blockIdx.x;              // ((n*G + g)*H + h)

    const int h = blk % H_;
    const int g = (blk / H_) % G_;
    const int n = blk / (H_ * G_);

    const size_t rowbase = (size_t)(n * C_ + g * CPG) * HW + (size_t)h * W_;

    // zero the R pads: 96 f4, one ds_write for tid<96
    if (tid < CPG * (PAD / 4)) {
        const int c = tid / 12, p4 = tid % 12;
        *(f4*)&Rs[c * RW + p4 * 4] = (f4)(0.0f);
    }

    // ---- stage global -> LDS via direct DMA (R6's proven staging, unchanged) ----
    // Wave w DMAs channels {w, w+4}: 640 B per (input, channel) row = 40 lanes x 16 B.
    if (lane < 40) {
        #pragma unroll
        for (int k = 0; k < 2; ++k) {
            const int c = wid + k * 4;
            const float* gl = Lg + rowbase + (size_t)c * HW + lane * 4;
            const float* gr = Rg + rowbase + (size_t)c * HW + lane * 4;
            __builtin_amdgcn_global_load_lds(
                (const __attribute__((address_space(1))) void*)gl,
                (__attribute__((address_space(3))) void*)&Ls[c * W_], 16, 0, 0);
            __builtin_amdgcn_global_load_lds(
                (const __attribute__((address_space(1))) void*)gr,
                (__attribute__((address_space(3))) void*)&Rs[c * RW + PAD], 16, 0, 0);
        }
    }
    __syncthreads();

    // ---- compute: one 4w x 8d tile per thread (tid < 240) ----
    // LDS reads per output: 4 b128 per channel per 32 outputs = 16 B/elem (was 24).
    if (tid < TILES) {
        const int tw = tid / 6;
        const int td = tid % 6;
        const int w0 = tw * 4;
        const int d0 = td * 8;
        const int r0 = w0 - d0 + PAD;   // [8, 204]; reads r0-8 .. r0+3 within [0, 207]

        f4 acc[4][2] = {};

        #pragma unroll
        for (int c = 0; c < CPG; ++c) {
            const f4 lv = *(const f4*)&Ls[c * W_ + w0];
            const float* rp = &Rs[c * RW + (r0 - 8)];   // 16B-aligned (r0 % 4 == 0)
            const f4 ra = *(const f4*)(rp);
            const f4 rb = *(const f4*)(rp + 4);
            const f4 rc = *(const f4*)(rp + 8);
            float rr[12];
            #pragma unroll
            for (int k = 0; k < 4; ++k) { rr[k] = ra[k]; rr[4 + k] = rb[k]; rr[8 + k] = rc[k]; }
            // out(w0+i, d0+j) += L[w0+i] * R[r0 + i - j] -> rr[8 + i - j], indices 1..11
            #pragma unroll
            for (int i = 0; i < 4; ++i) {
                #pragma unroll
                for (int j = 0; j < 8; ++j) {
                    acc[i][j >> 2][j & 3] += lv[i] * rr[8 + i - j];
                }
            }
        }

        float* op = out + (size_t)blk * (W_ * D_) + (size_t)w0 * D_ + d0;
        #pragma unroll
        for (int i = 0; i < 4; ++i) {
            *(f4*)(op + i * D_)     = acc[i][0] * 0.125f;
            *(f4*)(op + i * D_ + 4) = acc[i][1] * 0.125f;
        }
    }
}

extern "C" void kernel_launch(void* const* d_in, const int* in_sizes, int n_in,
                              void* d_out, int out_size, void* d_ws, size_t ws_size,
                              hipStream_t stream) {
    const float* Lg = (const float*)d_in[0];
    const float* Rg = (const float*)d_in[1];
    float* out = (float*)d_out;

    const int nblocks = N_ * G_ * H_;   // 12800 blocks, one per (n, g, h)
    gw_cost_kernel<<<dim3(nblocks), dim3(256), 0, stream>>>(Lg, Rg, out);
}